// Round 1
// baseline (8277.123 us; speedup 1.0000x reference)
//
#include <hip/hip_runtime.h>
#include <stdint.h>

// Problem constants
#define Bsz 16
#define Tlen 800
#define EPROJS 512
#define DUNITS 1024
#define ATT 512
#define ODIM 5000
#define LMAX 96
#define OL 97               // LMAX+1 decode steps
#define NTOK (OL*Bsz)       // 1552 tokens
#define G4 (4*DUNITS)       // 4096 gate rows
#define KX 1536             // [z0(1024) ; att_c(512)]
#define KA1 2048            // [z0'(1024) ; z1(1024)]
#define SOS_ID (ODIM-1)

typedef unsigned short u16;
typedef short bfrag8 __attribute__((ext_vector_type(8)));   // 8 bf16 in 4 VGPRs
typedef float f32x4 __attribute__((ext_vector_type(4)));

__device__ __forceinline__ float bf2f(u16 u){
  union { uint32_t u; float f; } v; v.u = ((uint32_t)u) << 16; return v.f;
}
__device__ __forceinline__ u16 f2bf(float f){
  union { float f; uint32_t u; } v; v.f = f;
  uint32_t r = v.u + 0x7FFFu + ((v.u >> 16) & 1u);   // RNE
  return (u16)(r >> 16);
}
__device__ __forceinline__ float sigm(float x){ return 1.0f/(1.0f + __expf(-x)); }
__device__ __forceinline__ float tanh_f(float x){ return 1.0f - 2.0f/(__expf(2.0f*x) + 1.0f); }

// One 16x16 C-tile per wave: C = A(16,K)bf16 @ B(16 rows of K)bf16^T, fp32 acc.
// A-frag: A[m=lane&15][k0+(lane>>4)*8+j] ; B-frag: B[n=lane&15][k0+...]
// D: row m=(lane>>4)*4+r, col n=lane&15   (verified gfx950 layout)
__device__ __forceinline__ f32x4 mfma_loop(const u16* A, int lda,
                                           const u16* Bm, int ldb,
                                           int K, f32x4 acc){
  int lane = threadIdx.x & 63;
  const u16* pa = A + (size_t)(lane & 15) * lda + ((lane >> 4) * 8);
  const u16* pb = Bm + (size_t)(lane & 15) * ldb + ((lane >> 4) * 8);
  #pragma unroll 4
  for (int k = 0; k < K; k += 32){
    bfrag8 av = *(const bfrag8*)(pa + k);
    bfrag8 bv = *(const bfrag8*)(pb + k);
    acc = __builtin_amdgcn_mfma_f32_16x16x32_bf16(av, bv, acc, 0, 0, 0);
  }
  return acc;
}

// ---------------- setup kernels ----------------
__global__ __launch_bounds__(256) void k_zero(float* p, int n){
  int i = blockIdx.x*256 + threadIdx.x;
  if (i < n) p[i] = 0.f;
}
__global__ __launch_bounds__(256) void k_cvt(const float* src, u16* dst, int n){
  int i = blockIdx.x*256 + threadIdx.x, st = gridDim.x*256;
  for (; i < n; i += st) dst[i] = f2bf(src[i]);
}
// Wcat0[j][k] : k<1024 -> W_hh0[j][k] ; else W_ih0[j][k] (att cols 1024..1535)
__global__ __launch_bounds__(256) void k_build_wcat0(const float* Whh0, const float* Wih0, u16* out){
  int i = blockIdx.x*256+threadIdx.x, n = G4*KX, st = gridDim.x*256;
  for (; i<n; i+=st){
    int j = i / KX, k = i % KX;
    float v = (k < DUNITS) ? Whh0[j*DUNITS + k] : Wih0[(size_t)j*KX + k];
    out[i] = f2bf(v);
  }
}
// Wcat1[j][k] : k<1024 -> W_ih1[j][k] ; else W_hh1[j][k-1024]
__global__ __launch_bounds__(256) void k_build_wcat1(const float* Wih1, const float* Whh1, u16* out){
  int i = blockIdx.x*256+threadIdx.x, n = G4*KA1, st = gridDim.x*256;
  for (; i<n; i+=st){
    int j = i / KA1, k = i % KA1;
    float v = (k < DUNITS) ? Wih1[j*DUNITS + k] : Whh1[j*DUNITS + (k - DUNITS)];
    out[i] = f2bf(v);
  }
}
__global__ __launch_bounds__(256) void k_build_wih0e(const float* Wih0, u16* out){
  int i = blockIdx.x*256+threadIdx.x, n = G4*DUNITS, st = gridDim.x*256;
  for (; i<n; i+=st){
    int j = i/DUNITS, k = i%DUNITS;
    out[i] = f2bf(Wih0[(size_t)j*KX + k]);
  }
}
// A_ey[n][k] = embed[ys_in[b,l]][k] bf16, n = l*16+b
__global__ __launch_bounds__(256) void k_build_aey(const float* embed, const int* ys_pad, u16* out){
  int i = blockIdx.x*256+threadIdx.x, n = NTOK*DUNITS, st = gridDim.x*256;
  for (; i<n; i+=st){
    int row = i / DUNITS, k = i % DUNITS;
    int l = row / Bsz, b = row % Bsz;
    int idx = (l == 0) ? SOS_ID : ys_pad[b*LMAX + (l-1)];
    out[i] = f2bf(embed[(size_t)idx*DUNITS + k]);
  }
}

// pre_enc(bf16) = hs @ W_enc^T + b_enc   (M=12800,N=512,K=512)
__global__ __launch_bounds__(64) void k_gemm_preenc(const u16* hsb, const u16* Wenc,
                                                    const float* b_enc, u16* pre_enc){
  int bid = blockIdx.x;
  int m0 = (bid >> 5) * 16, n0 = (bid & 31) * 16;
  int lane = threadIdx.x & 63;
  int col = n0 + (lane & 15);
  float bias = b_enc[col];
  f32x4 acc = {bias, bias, bias, bias};
  acc = mfma_loop(hsb + (size_t)m0*EPROJS, EPROJS, Wenc + (size_t)n0*EPROJS, EPROJS, EPROJS, acc);
  int quad = lane >> 4;
  #pragma unroll
  for (int r = 0; r < 4; r++)
    pre_enc[(size_t)(m0 + quad*4 + r)*ATT + col] = f2bf(acc[r]);
}

// pre_gate0(f32) = A_ey @ W_ih0[:, :1024]^T + b_ih0 + b_hh0   (M=1552,N=4096,K=1024)
__global__ __launch_bounds__(64) void k_gemm_pregate(const u16* Aey, const u16* Wih0e,
                                                     const float* b_ih0, const float* b_hh0, float* out){
  int bid = blockIdx.x;
  int m0 = (bid >> 8) * 16, n0 = (bid & 255) * 16;
  int lane = threadIdx.x & 63;
  int col = n0 + (lane & 15);
  float bias = b_ih0[col] + b_hh0[col];
  f32x4 acc = {bias, bias, bias, bias};
  acc = mfma_loop(Aey + (size_t)m0*DUNITS, DUNITS, Wih0e + (size_t)n0*DUNITS, DUNITS, DUNITS, acc);
  int quad = lane >> 4;
  #pragma unroll
  for (int r = 0; r < 4; r++)
    out[(size_t)(m0 + quad*4 + r)*G4 + col] = acc[r];
}

// logits(f32) = z_all @ W_out^T + b_out   (M=1552,N=5000(guarded),K=1024)
__global__ __launch_bounds__(64) void k_gemm_logits(const u16* zall, const u16* Woutb,
                                                    const float* b_out, float* logits){
  const int NT = 313;   // ceil(5000/16)
  int bid = blockIdx.x;
  int m0 = (bid / NT) * 16, n0 = (bid % NT) * 16;
  int lane = threadIdx.x & 63;
  int col = n0 + (lane & 15);
  bool ok = col < ODIM;
  int brow = ok ? col : 0;  // clamped row only pollutes unsampled columns
  float bias = ok ? b_out[col] : 0.f;
  f32x4 acc = {bias, bias, bias, bias};
  const u16* pa = zall + (size_t)m0*DUNITS + (size_t)(lane & 15)*DUNITS + (lane >> 4)*8;
  const u16* pb = Woutb + (size_t)brow*DUNITS + (lane >> 4)*8;
  #pragma unroll 4
  for (int k = 0; k < DUNITS; k += 32){
    bfrag8 av = *(const bfrag8*)(pa + k);
    bfrag8 bv = *(const bfrag8*)(pb + k);
    acc = __builtin_amdgcn_mfma_f32_16x16x32_bf16(av, bv, acc, 0, 0, 0);
  }
  int quad = lane >> 4;
  if (ok){
    #pragma unroll
    for (int r = 0; r < 4; r++)
      logits[(size_t)(m0 + quad*4 + r)*ODIM + col] = acc[r];
  }
}

// ---------------- recurrence kernels ----------------
#define EP_CHUNK 64
#define EP_NCH 13
#define EP_WGS (Bsz*EP_NCH)   // 208

// e/p-role: p[b,t] = exp(2 * gvec.tanh(pre_enc + dec_proj)), S[b] += sum
// cell1-role (bid>=EP_WGS, l>0): apply gates1 of step l-1 -> z1_l, c1
__global__ __launch_bounds__(256) void k_step_ep(
    const u16* pre_enc, const float* dp, const float* gvec, const int* hlens,
    float* p, float* S,
    const float* gates1, float* c1, u16* a1, u16* zall, int l)
{
  int bid = blockIdx.x;
  if (bid < EP_WGS){
    int b = bid / EP_NCH, ch = bid % EP_NCH;
    int t0 = ch * EP_CHUNK;
    __shared__ float dps[ATT], gvs[ATT];
    for (int i = threadIdx.x; i < ATT; i += 256){
      dps[i] = dp[b*ATT + i];
      gvs[i] = gvec[i];
    }
    __syncthreads();
    int wave = threadIdx.x >> 6, lane = threadIdx.x & 63;
    int hl = hlens[b];
    float sp = 0.f;
    for (int ti = 0; ti < 16; ti++){
      int t = t0 + wave*16 + ti;
      if (t >= Tlen) break;
      float acc = 0.f;
      if (t < hl){
        const u16* pe = pre_enc + ((size_t)(b*Tlen + t))*ATT + lane*8;
        bfrag8 v = *(const bfrag8*)pe;
        #pragma unroll
        for (int j = 0; j < 8; j++){
          float x = bf2f(((u16*)&v)[j]) + dps[lane*8 + j];
          acc += gvs[lane*8 + j] * tanh_f(x);
        }
      }
      #pragma unroll
      for (int off = 32; off > 0; off >>= 1) acc += __shfl_xor(acc, off, 64);
      float pv = (t < hl) ? __expf(2.0f * acc) : 0.f;   // SCALING=2, no max needed (|2e|<=~16)
      if (lane == 0){ p[b*Tlen + t] = pv; sp += pv; }
    }
    if (lane == 0 && sp != 0.f) atomicAdd(&S[b], sp);
  } else {
    int idx = (bid - EP_WGS)*256 + threadIdx.x;  // 0..16383
    int b = idx >> 10, d = idx & 1023;
    float gi = gates1[b*G4 + d];
    float gf = gates1[b*G4 + DUNITS + d];
    float gg = gates1[b*G4 + 2*DUNITS + d];
    float go = gates1[b*G4 + 3*DUNITS + d];
    float c = c1[idx];
    float cn = sigm(gf)*c + sigm(gi)*tanh_f(gg);
    float h  = sigm(go)*tanh_f(cn);
    c1[idx] = cn;
    u16 hb = f2bf(h);
    a1[b*KA1 + DUNITS + d] = hb;                       // z1 slot for gates1
    zall[(size_t)((l-1)*Bsz + b)*DUNITS + d] = hb;     // scan output row l-1
  }
}

// att_c[b,e] = sum_t p[b,t]*hs[b,t,e] / S[b]  -> bf16 into x_buf[:,1024:1536]
__global__ __launch_bounds__(256) void k_step_attc(
    const u16* hsb, const float* p, const float* S, u16* x_buf)
{
  int bid = blockIdx.x;            // 256 = 16 b * 8 echunks of 64? -> 16 b * 16 chunks of 32
  int b = bid >> 4, e0 = (bid & 15) * 32;
  int tsub = threadIdx.x >> 5, el = threadIdx.x & 31;
  int e = e0 + el;
  float acc = 0.f;
  for (int t = tsub; t < Tlen; t += 8)
    acc += p[b*Tlen + t] * bf2f(hsb[((size_t)(b*Tlen + t))*EPROJS + e]);
  __shared__ float red[256];
  red[threadIdx.x] = acc;
  __syncthreads();
  if (tsub == 0){
    float s = acc;
    #pragma unroll
    for (int j = 1; j < 8; j++) s += red[j*32 + el];
    x_buf[b*KX + DUNITS + e0 + el] = f2bf(s / S[b]);
  }
}

// gates0 = pre_gate0[l] + [z0;att_c] @ [W_hh0 || W_ih0_att]^T
__global__ __launch_bounds__(64) void k_step_g0(
    const u16* x_buf, const u16* Wcat0, const float* pre_gate0, float* gates0, int l)
{
  int j0 = blockIdx.x * 16;
  int lane = threadIdx.x & 63;
  int col = j0 + (lane & 15), quad = lane >> 4;
  f32x4 acc;
  #pragma unroll
  for (int r = 0; r < 4; r++)
    acc[r] = pre_gate0[(size_t)(l*Bsz + quad*4 + r)*G4 + col];
  acc = mfma_loop(x_buf, KX, Wcat0 + (size_t)j0*KX, KX, KX, acc);
  #pragma unroll
  for (int r = 0; r < 4; r++) gates0[(quad*4 + r)*G4 + col] = acc[r];
}

// cell0: z0', c0; write z0' bf16 into x_buf[:, :1024] and a1[:, :1024]
__global__ __launch_bounds__(256) void k_step_cell0(
    const float* gates0, float* c0, u16* x_buf, u16* a1)
{
  int idx = blockIdx.x*256 + threadIdx.x;  // 16384
  int b = idx >> 10, d = idx & 1023;
  float gi = gates0[b*G4 + d];
  float gf = gates0[b*G4 + DUNITS + d];
  float gg = gates0[b*G4 + 2*DUNITS + d];
  float go = gates0[b*G4 + 3*DUNITS + d];
  float c = c0[idx];
  float cn = sigm(gf)*c + sigm(gi)*tanh_f(gg);
  float h  = sigm(go)*tanh_f(cn);
  c0[idx] = cn;
  u16 hb = f2bf(h);
  x_buf[b*KX + d] = hb;
  a1[b*KA1 + d] = hb;
}

// gates1 = [z0';z1] @ [W_ih1 || W_hh1]^T + b_ih1 + b_hh1   (blocks 0..255)
// dec_proj dp = z0' @ W_dec^T                              (blocks 256..287)
// also zeroes S for the next step
__global__ __launch_bounds__(64) void k_step_g1dp(
    const u16* a1, const u16* Wcat1, const float* b_ih1, const float* b_hh1,
    float* gates1, const u16* Wdec, float* dp, float* S)
{
  int bid = blockIdx.x;
  int lane = threadIdx.x & 63;
  int quad = lane >> 4;
  if (bid < 256){
    int j0 = bid*16, col = j0 + (lane & 15);
    float bias = b_ih1[col] + b_hh1[col];
    f32x4 acc = {bias, bias, bias, bias};
    acc = mfma_loop(a1, KA1, Wcat1 + (size_t)j0*KA1, KA1, KA1, acc);
    #pragma unroll
    for (int r = 0; r < 4; r++) gates1[(quad*4 + r)*G4 + col] = acc[r];
  } else {
    int w = bid - 256;                 // 0..31
    int j0 = w*16, col = j0 + (lane & 15);
    f32x4 acc = {0.f, 0.f, 0.f, 0.f};
    acc = mfma_loop(a1, KA1, Wdec + (size_t)j0*DUNITS, DUNITS, DUNITS, acc);  // K=1024: z0' part
    #pragma unroll
    for (int r = 0; r < 4; r++) dp[(quad*4 + r)*ATT + col] = acc[r];
    if (w == 0 && lane < Bsz) S[lane] = 0.f;
  }
}

__global__ __launch_bounds__(256) void k_cell1_tail(const float* gates1, float* c1, u16* zall){
  int idx = blockIdx.x*256 + threadIdx.x;
  int b = idx >> 10, d = idx & 1023;
  float gi = gates1[b*G4 + d];
  float gf = gates1[b*G4 + DUNITS + d];
  float gg = gates1[b*G4 + 2*DUNITS + d];
  float go = gates1[b*G4 + 3*DUNITS + d];
  float c = c1[idx];
  float cn = sigm(gf)*c + sigm(gi)*tanh_f(gg);
  float h  = sigm(go)*tanh_f(cn);
  c1[idx] = cn;
  zall[(size_t)(LMAX*Bsz + b)*DUNITS + d] = f2bf(h);
}

// per-token NLL: logsumexp(logits_row) - logits_row[target]
__global__ __launch_bounds__(256) void k_nll(const float* logits, const int* ys_pad, float* nll){
  int n = blockIdx.x;
  int b = n & 15, l = n >> 4;
  const float* row = logits + (size_t)n * ODIM;
  __shared__ float red[256];
  float m = -1e30f;
  for (int i = threadIdx.x; i < ODIM; i += 256) m = fmaxf(m, row[i]);
  red[threadIdx.x] = m; __syncthreads();
  for (int s = 128; s > 0; s >>= 1){
    if (threadIdx.x < s) red[threadIdx.x] = fmaxf(red[threadIdx.x], red[threadIdx.x + s]);
    __syncthreads();
  }
  float M = red[0]; __syncthreads();
  float sum = 0.f;
  for (int i = threadIdx.x; i < ODIM; i += 256) sum += __expf(row[i] - M);
  red[threadIdx.x] = sum; __syncthreads();
  for (int s = 128; s > 0; s >>= 1){
    if (threadIdx.x < s) red[threadIdx.x] += red[threadIdx.x + s];
    __syncthreads();
  }
  if (threadIdx.x == 0){
    int tgt = (l < LMAX) ? ys_pad[b*LMAX + l] : (ODIM - 1);
    nll[n] = (M + __logf(red[0])) - row[tgt];
  }
}

__global__ __launch_bounds__(256) void k_loss(const float* nll, float* out){
  __shared__ float red[256];
  float s = 0.f;
  for (int i = threadIdx.x; i < NTOK; i += 256) s += nll[i];
  red[threadIdx.x] = s; __syncthreads();
  for (int st = 128; st > 0; st >>= 1){
    if (threadIdx.x < st) red[threadIdx.x] += red[threadIdx.x + st];
    __syncthreads();
  }
  if (threadIdx.x == 0) out[0] = red[0] * ((float)LMAX / (float)NTOK);
}

extern "C" void kernel_launch(void* const* d_in, const int* in_sizes, int n_in,
                              void* d_out, int out_size, void* d_ws, size_t ws_size,
                              hipStream_t stream)
{
  const float* hs     = (const float*)d_in[0];
  const int*   hlens  = (const int*)d_in[1];
  const int*   ys_pad = (const int*)d_in[2];
  const float* embed  = (const float*)d_in[3];
  const float* W_ih0  = (const float*)d_in[4];
  const float* W_hh0  = (const float*)d_in[5];
  const float* b_ih0  = (const float*)d_in[6];
  const float* b_hh0  = (const float*)d_in[7];
  const float* W_ih1  = (const float*)d_in[8];
  const float* W_hh1  = (const float*)d_in[9];
  const float* b_ih1  = (const float*)d_in[10];
  const float* b_hh1  = (const float*)d_in[11];
  const float* W_enc  = (const float*)d_in[12];
  const float* b_enc  = (const float*)d_in[13];
  const float* W_dec  = (const float*)d_in[14];
  const float* gvec   = (const float*)d_in[15];
  const float* W_out  = (const float*)d_in[16];
  const float* b_out  = (const float*)d_in[17];
  (void)in_sizes; (void)n_in; (void)out_size; (void)ws_size;

  char* w = (char*)d_ws;
  size_t off = 0;
  auto alloc = [&](size_t bytes)->char*{
    char* ptr = w + off;
    off += (bytes + 255) & ~(size_t)255;
    return ptr;
  };
  // --- state block (zeroed every launch) ---
  float* c0   = (float*)alloc(Bsz*DUNITS*4);
  float* c1   = (float*)alloc(Bsz*DUNITS*4);
  float* dp   = (float*)alloc(Bsz*ATT*4);
  float* S    = (float*)alloc(Bsz*4);
  u16*  xbuf  = (u16*)alloc(Bsz*KX*2);
  u16*  a1    = (u16*)alloc(Bsz*KA1*2);
  size_t state_bytes = off;
  // --- scratch / staged tensors ---
  float* p     = (float*)alloc(Bsz*Tlen*4);
  float* g0    = (float*)alloc(Bsz*G4*4);
  float* g1    = (float*)alloc(Bsz*G4*4);
  u16*  hsb    = (u16*)alloc((size_t)Bsz*Tlen*EPROJS*2);
  u16*  peb    = (u16*)alloc((size_t)Bsz*Tlen*ATT*2);
  u16*  wencb  = (u16*)alloc((size_t)ATT*EPROJS*2);
  u16*  wdecb  = (u16*)alloc((size_t)ATT*DUNITS*2);
  u16*  wc0    = (u16*)alloc((size_t)G4*KX*2);
  u16*  wc1    = (u16*)alloc((size_t)G4*KA1*2);
  u16*  wih0e  = (u16*)alloc((size_t)G4*DUNITS*2);
  u16*  woutb  = (u16*)alloc((size_t)ODIM*DUNITS*2);
  u16*  aey    = (u16*)alloc((size_t)NTOK*DUNITS*2);
  float* pg0   = (float*)alloc((size_t)NTOK*G4*4);
  u16*  zall   = (u16*)alloc((size_t)NTOK*DUNITS*2);
  float* logits= (float*)alloc((size_t)NTOK*ODIM*4);
  float* nll   = (float*)alloc(NTOK*4);

  // zero the recurrent state (ws is poisoned 0xAA before every call)
  {
    int n = (int)(state_bytes / 4);
    k_zero<<<(n + 255)/256, 256, 0, stream>>>((float*)w, n);
  }

  // stage bf16 operands
  k_cvt<<<2048,256,0,stream>>>(hs, hsb, Bsz*Tlen*EPROJS);
  k_cvt<<<256,256,0,stream>>>(W_enc, wencb, ATT*EPROJS);
  k_cvt<<<512,256,0,stream>>>(W_dec, wdecb, ATT*DUNITS);
  k_cvt<<<2048,256,0,stream>>>(W_out, woutb, ODIM*DUNITS);
  k_build_wcat0<<<2048,256,0,stream>>>(W_hh0, W_ih0, wc0);
  k_build_wcat1<<<2048,256,0,stream>>>(W_ih1, W_hh1, wc1);
  k_build_wih0e<<<2048,256,0,stream>>>(W_ih0, wih0e);
  k_build_aey<<<1024,256,0,stream>>>(embed, ys_pad, aey);

  // one-time GEMMs
  k_gemm_preenc<<<(Bsz*Tlen/16)*(ATT/16), 64, 0, stream>>>(hsb, wencb, b_enc, peb);
  k_gemm_pregate<<<OL*(G4/16), 64, 0, stream>>>(aey, wih0e, b_ih0, b_hh0, pg0);

  // 97-step recurrence
  for (int l = 0; l < OL; l++){
    int epgrid = (l == 0) ? EP_WGS : (EP_WGS + 64);
    k_step_ep<<<epgrid, 256, 0, stream>>>(peb, dp, gvec, hlens, p, S, g1, c1, a1, zall, l);
    k_step_attc<<<256, 256, 0, stream>>>(hsb, p, S, xbuf);
    k_step_g0<<<256, 64, 0, stream>>>(xbuf, wc0, pg0, g0, l);
    k_step_cell0<<<64, 256, 0, stream>>>(g0, c0, xbuf, a1);
    k_step_g1dp<<<288, 64, 0, stream>>>(a1, wc1, b_ih1, b_hh1, g1, wdecb, dp, S);
  }
  k_cell1_tail<<<64,256,0,stream>>>(g1, c1, zall);

  // output projection + loss
  k_gemm_logits<<<OL*313, 64, 0, stream>>>(zall, woutb, b_out, logits);
  k_nll<<<NTOK,256,0,stream>>>(logits, ys_pad, nll);
  k_loss<<<1,256,0,stream>>>(nll, (float*)d_out);
}